// Round 4
// baseline (1758.030 us; speedup 1.0000x reference)
//
#include <hip/hip_runtime.h>
#include <hip/hip_bf16.h>
#include <math.h>

#define BB 8
#define SS 512
#define LIN_SCALE 0.044194173824159216f   // 1/sqrt(512)
#define CONV_SCALE 0.041666666666666664f  // 1/sqrt(64*9)
#define SQRT2 1.4142135623730951f

typedef __attribute__((ext_vector_type(8))) short short8;
typedef __attribute__((ext_vector_type(16))) float f32x16;

__device__ __forceinline__ ushort bf16h(float v) {
    unsigned u = __float_as_uint(v);
    return (ushort)((u + 0x7fffu + ((u >> 16) & 1u)) >> 16);
}
__device__ __forceinline__ void splitv(float v, ushort& h, ushort& l) {
    h = bf16h(v);
    l = bf16h(v - __uint_as_float((unsigned)h << 16));
}
__device__ __forceinline__ float b2f(ushort u) { return __uint_as_float((unsigned)u << 16); }

// ---------------------------------------------------------------------------
// prep kernels
// ---------------------------------------------------------------------------
__global__ void zero_k(float* z) { z[threadIdx.x] = 0.f; }   // 64 thr -> 256 B

// NCHW fp32 -> channels-last bf16 hi/lo planes
__global__ __launch_bounds__(256) void tocl_k(const float* __restrict__ x,
                                              ushort* __restrict__ oH, ushort* __restrict__ oL) {
    __shared__ float tile[64][65];
    const int blk = blockIdx.x;                  // 8*256*4
    const int b = blk >> 10, rem = blk & 1023;
    const int y = rem >> 2, x0 = (rem & 3) << 6;
    const int tid = threadIdx.x, lane = tid & 63, g = tid >> 6;
    const float* xb = x + ((size_t)b << 22) + (y << 8) + x0;
    #pragma unroll
    for (int i = 0; i < 16; ++i) {
        int c = i * 4 + g;
        tile[c][lane] = xb[((size_t)c << 16) + lane];
    }
    __syncthreads();
    const size_t pixbase = ((size_t)b << 16) + (y << 8) + x0;
    #pragma unroll
    for (int i = 0; i < 16; ++i) {
        int xx = i * 4 + g;
        ushort h, l; splitv(tile[lane][xx], h, l);
        size_t idx = (pixbase + xx) * 64 + lane;
        oH[idx] = h; oL[idx] = l;
    }
}

// Weight image layout == LDS layout: per chunk cc (16 cins), 16B-slot index
// s2 = t*256 + co*4 + sp (sp = stored/physical slot); logical slot
// slog = sp ^ ((co>>1)&3); plane = slog>>1 (H/L), chalf = slog&1;
// slot holds cins [cc*16 + chalf*8, +8).
__device__ __forceinline__ void wdecode(int i, int& cc, int& t, int& co, int& ci, int& pl) {
    int e = i & 7;
    int s = i >> 3;             // 16B slot, 0..9215
    cc = s / 2304;
    int s2 = s % 2304;
    t = s2 >> 8;
    int co8 = s2 & 255;
    co = co8 >> 2;
    int sp = co8 & 3;
    int slog = sp ^ ((co >> 1) & 3);
    pl = slog >> 1;
    ci = cc * 16 + (slog & 1) * 8 + e;
}

__global__ void packw_k(const float* __restrict__ w, ushort* __restrict__ img) {
    int i = blockIdx.x * 256 + threadIdx.x;      // 73728
    if (i >= 73728) return;
    int cc, t, co, ci, pl;
    wdecode(i, cc, t, co, ci, pl);
    ushort h, l; splitv(w[(co * 64 + ci) * 9 + t], h, l);
    img[i] = pl ? l : h;
}

__global__ void style_s_k(const float* __restrict__ style, const float* __restrict__ mod_w,
                          const float* __restrict__ mod_b, float* __restrict__ sbuf) {
    int tid = threadIdx.x;                       // 512
    int b = tid >> 6, cin = tid & 63;
    float acc = 0.f;
    for (int j = 0; j < SS; ++j) acc += style[b * SS + j] * mod_w[cin * SS + j];
    sbuf[b * 64 + cin] = acc * LIN_SCALE + mod_b[cin];
}

__global__ void demod_k(const float* __restrict__ conv_w, const float* __restrict__ sbuf,
                        float* __restrict__ demod) {
    int tid = threadIdx.x;                       // 512
    int b = tid >> 6, cout = tid & 63;
    float sum = 0.f;
    for (int cin = 0; cin < 64; ++cin) {
        float m = CONV_SCALE * sbuf[b * 64 + cin];
        const float* wp = conv_w + (cout * 64 + cin) * 9;
        #pragma unroll
        for (int k = 0; k < 9; ++k) { float v = wp[k] * m; sum += v * v; }
    }
    demod[b * 64 + cout] = 1.0f / sqrtf(sum + 1e-8f);
}

__global__ void packmod_k(const float* __restrict__ conv_w, const float* __restrict__ sbuf,
                          const float* __restrict__ demod, ushort* __restrict__ img) {
    int i = blockIdx.x * 256 + threadIdx.x;      // 589824
    if (i >= 589824) return;
    int b = i / 73728, ii = i % 73728;
    int cc, t, co, ci, pl;
    wdecode(ii, cc, t, co, ci, pl);
    float v = CONV_SCALE * conv_w[(co * 64 + ci) * 9 + t] * sbuf[b * 64 + ci] * demod[b * 64 + co];
    ushort h, l; splitv(v, h, l);
    img[i] = pl ? l : h;
}

// ---------------------------------------------------------------------------
// MFMA conv: 3x3 C64->C64 SAME. Inputs: pre-split bf16 H/L channels-last.
// Block 256 thr = 4 waves, tile 8 rows x 32 px, 64 couts; per wave 2x2
// 32x32x16 frags. B-fragments loaded DIRECTLY global->VGPR (L1/L2 cached,
// no input LDS). LDS holds only the current 16-cin weight chunk (36864 B,
// 4 blocks/CU by LDS), staged via global_load_lds, 2-bit slot swizzle for
// conflict-free ds_read_b128.
// EPI: 0 = PReLU->pair, 1 = +resid(pair)->pair, 2 = fusedLReLU->NCHW fp32.
// ---------------------------------------------------------------------------
#define GLDS(gsrc, ldst) __builtin_amdgcn_global_load_lds( \
    (const __attribute__((address_space(1))) unsigned int*)(gsrc), \
    (__attribute__((address_space(3))) unsigned int*)(ldst), 16, 0, 0)

#define VWAIT0 asm volatile("s_waitcnt vmcnt(0)" ::: "memory")
#define BAR    __builtin_amdgcn_s_barrier()

template <int EPI, int PERB>
__global__ __launch_bounds__(256, 3)
void mconv_k(const ushort* __restrict__ inH, const ushort* __restrict__ inL,
             const char* __restrict__ wimg, const float* __restrict__ aux,
             const ushort* __restrict__ rH, const ushort* __restrict__ rL,
             ushort* __restrict__ oH, ushort* __restrict__ oL,
             float* __restrict__ onchw, const ushort* __restrict__ zb) {
    __shared__ __align__(16) char lds[36864];
    const int tid = threadIdx.x;
    const int orig = blockIdx.x;
    const int blk = (orig & 7) * 256 + (orig >> 3);   // XCD swizzle: batch per XCD
    const int b = blk >> 8, t8 = blk & 255;
    const int y0 = (t8 >> 3) << 3, x0 = (t8 & 7) << 5;
    const int wv = tid >> 6, l = tid & 63, ln = l & 31, lh = l >> 5;

    const char* wsrc = wimg + (PERB ? (size_t)b * 147456 : 0);
    // A-read offsets: entry(t,co) = 64B at t*4096 + co*64; slot phys = slog ^ ((co>>1)&3)
    const int swz = (ln >> 1) & 3;
    const int offH = ln * 64 + ((lh ^ swz) << 4);          // H-plane frag (slog = lh)
    const int offL = ln * 64 + (((2 + lh) ^ swz) << 4);    // L-plane frag (slog = 2+lh)

    f32x16 acc[2][2];
    #pragma unroll
    for (int m = 0; m < 2; ++m)
        #pragma unroll
        for (int j = 0; j < 2; ++j) acc[m][j] = (f32x16)(0.0f);

#define ISSUE_W(c) { _Pragma("unroll") for (int r = 0; r < 9; ++r) \
    GLDS(wsrc + (c) * 36864 + r * 4096 + tid * 16, lds + r * 4096 + (tid & 192) * 16); }

    ISSUE_W(0); VWAIT0; BAR;

    #pragma unroll
    for (int c = 0; c < 4; ++c) {
        const int c0 = c * 16 + lh * 8;
        #pragma unroll
        for (int dx = 0; dx < 3; ++dx) {
            short8 bH[4], bL[4];
            #pragma unroll
            for (int r = 0; r < 4; ++r) {
                const int gy = y0 + 2 * wv - 1 + r;
                const int gx = x0 + ln + dx - 1;
                const bool valid = ((unsigned)gy < 256u) & ((unsigned)gx < 256u);
                const size_t poff = ((((size_t)b << 16) + ((size_t)(gy & 255) << 8) + (gx & 255)) << 6) + c0;
                const ushort* pH = valid ? inH + poff : zb;
                const ushort* pL = valid ? inL + poff : zb;
                bH[r] = *(const short8*)pH;
                bL[r] = *(const short8*)pL;
            }
            #pragma unroll
            for (int dy = 0; dy < 3; ++dy) {
                const char* WA = lds + (dy * 3 + dx) * 4096;
                short8 aH0 = *(const short8*)(WA + offH);
                short8 aH1 = *(const short8*)(WA + offH + 2048);
                short8 aL0 = *(const short8*)(WA + offL);
                short8 aL1 = *(const short8*)(WA + offL + 2048);
                #pragma unroll
                for (int j = 0; j < 2; ++j) {
                    const int r = j + dy;
                    acc[0][j] = __builtin_amdgcn_mfma_f32_32x32x16_bf16(aH0, bH[r], acc[0][j], 0, 0, 0);
                    acc[0][j] = __builtin_amdgcn_mfma_f32_32x32x16_bf16(aH0, bL[r], acc[0][j], 0, 0, 0);
                    acc[0][j] = __builtin_amdgcn_mfma_f32_32x32x16_bf16(aL0, bH[r], acc[0][j], 0, 0, 0);
                    acc[1][j] = __builtin_amdgcn_mfma_f32_32x32x16_bf16(aH1, bH[r], acc[1][j], 0, 0, 0);
                    acc[1][j] = __builtin_amdgcn_mfma_f32_32x32x16_bf16(aH1, bL[r], acc[1][j], 0, 0, 0);
                    acc[1][j] = __builtin_amdgcn_mfma_f32_32x32x16_bf16(aL1, bH[r], acc[1][j], 0, 0, 0);
                }
            }
        }
        BAR;                                   // all waves done reading this chunk's weights
        if (c < 3) { ISSUE_W(c + 1); VWAIT0; BAR; }
    }
#undef ISSUE_W

    // ---- epilogue: C/D col = ln(px), row = 8q + 4lh + (0..3), +32m ----
    #pragma unroll
    for (int m = 0; m < 2; ++m)
        #pragma unroll
        for (int j = 0; j < 2; ++j) {
            const int yo = y0 + 2 * wv + j;
            const size_t pix = ((size_t)b << 16) + ((size_t)yo << 8) + x0 + ln;
            #pragma unroll
            for (int q = 0; q < 4; ++q) {
                const int co0 = m * 32 + 8 * q + 4 * lh;
                float v0 = acc[m][j][4 * q + 0], v1 = acc[m][j][4 * q + 1];
                float v2 = acc[m][j][4 * q + 2], v3 = acc[m][j][4 * q + 3];
                if (EPI == 0) {
                    float4 al = *(const float4*)(aux + co0);
                    v0 = v0 > 0.f ? v0 : al.x * v0;
                    v1 = v1 > 0.f ? v1 : al.y * v1;
                    v2 = v2 > 0.f ? v2 : al.z * v2;
                    v3 = v3 > 0.f ? v3 : al.w * v3;
                } else if (EPI == 1) {
                    const size_t ca = pix * 64 + co0;
                    ushort4 rh = *(const ushort4*)(rH + ca);
                    ushort4 rl = *(const ushort4*)(rL + ca);
                    v0 += b2f(rh.x) + b2f(rl.x);
                    v1 += b2f(rh.y) + b2f(rl.y);
                    v2 += b2f(rh.z) + b2f(rl.z);
                    v3 += b2f(rh.w) + b2f(rl.w);
                } else {
                    float4 bi = *(const float4*)(aux + co0);
                    float ob;
                    ob = v0 + bi.x; v0 = (ob > 0.f ? ob : 0.2f * ob) * SQRT2;
                    ob = v1 + bi.y; v1 = (ob > 0.f ? ob : 0.2f * ob) * SQRT2;
                    ob = v2 + bi.z; v2 = (ob > 0.f ? ob : 0.2f * ob) * SQRT2;
                    ob = v3 + bi.w; v3 = (ob > 0.f ? ob : 0.2f * ob) * SQRT2;
                }
                if (EPI == 2) {
                    const size_t sp = ((size_t)yo << 8) + x0 + ln;
                    onchw[(((size_t)(b * 64 + co0 + 0)) << 16) + sp] = v0;
                    onchw[(((size_t)(b * 64 + co0 + 1)) << 16) + sp] = v1;
                    onchw[(((size_t)(b * 64 + co0 + 2)) << 16) + sp] = v2;
                    onchw[(((size_t)(b * 64 + co0 + 3)) << 16) + sp] = v3;
                } else {
                    ushort4 h4, l4;
                    splitv(v0, h4.x, l4.x); splitv(v1, h4.y, l4.y);
                    splitv(v2, h4.z, l4.z); splitv(v3, h4.w, l4.w);
                    const size_t ca = pix * 64 + co0;
                    *(ushort4*)(oH + ca) = h4;
                    *(ushort4*)(oL + ca) = l4;
                }
            }
        }
}

// ---------------------------------------------------------------------------
// Host launch
// ---------------------------------------------------------------------------
extern "C" void kernel_launch(void* const* d_in, const int* in_sizes, int n_in,
                              void* d_out, int out_size, void* d_ws, size_t ws_size,
                              hipStream_t stream) {
    const float* x       = (const float*)d_in[0];
    const float* style   = (const float*)d_in[1];
    const float* w1a     = (const float*)d_in[2];
    const float* alpha1  = (const float*)d_in[3];
    const float* w1b     = (const float*)d_in[4];
    const float* w2a     = (const float*)d_in[5];
    const float* alpha2  = (const float*)d_in[6];
    const float* w2b     = (const float*)d_in[7];
    const float* mod_w   = (const float*)d_in[8];
    const float* mod_b   = (const float*)d_in[9];
    const float* conv_w  = (const float*)d_in[10];
    const float* fused_b = (const float*)d_in[11];
    float* out = (float*)d_out;

    char* ws = (char*)d_ws;
    float*  zbf   = (float*)ws;                  // 256 B zero buffer
    float*  sbuf  = (float*)(ws + 256);          // 512 f
    float*  demod = (float*)(ws + 2304);         // 512 f
    ushort* wfix  = (ushort*)(ws + 4352);        // 4 x 147456 B images
    ushort* wmod  = (ushort*)(ws + 594176);      // 8 x 147456 B
    char*   pl    = ws + 1774080;
    const size_t PAIRB = 134217728ull;           // one H+L plane pair (bytes)
    const size_t PLEL  = 33554432ull;            // elements per plane

    ushort* XPH = (ushort*)pl;             ushort* XPL = XPH + PLEL;
    ushort* PBH = (ushort*)(pl + PAIRB);   ushort* PBL = PBH + PLEL;
    ushort *PAH, *PAL;
    if (ws_size >= 1774080ull + 3 * PAIRB) {
        PAH = (ushort*)(pl + 2 * PAIRB); PAL = PAH + PLEL;
    } else {
        PAH = (ushort*)d_out; PAL = PAH + PLEL;  // d_out hosts PA; rewritten by c5
    }
    const ushort* zb = (const ushort*)zbf;

    // --- prep ---
    hipLaunchKernelGGL(zero_k, dim3(1), dim3(64), 0, stream, zbf);
    hipLaunchKernelGGL(tocl_k, dim3(BB * 1024), dim3(256), 0, stream, x, XPH, XPL);
    hipLaunchKernelGGL(packw_k, dim3(288), dim3(256), 0, stream, w1a, wfix + 0 * 73728);
    hipLaunchKernelGGL(packw_k, dim3(288), dim3(256), 0, stream, w1b, wfix + 1 * 73728);
    hipLaunchKernelGGL(packw_k, dim3(288), dim3(256), 0, stream, w2a, wfix + 2 * 73728);
    hipLaunchKernelGGL(packw_k, dim3(288), dim3(256), 0, stream, w2b, wfix + 3 * 73728);
    hipLaunchKernelGGL(style_s_k, dim3(1), dim3(512), 0, stream, style, mod_w, mod_b, sbuf);
    hipLaunchKernelGGL(demod_k, dim3(1), dim3(512), 0, stream, conv_w, sbuf, demod);
    hipLaunchKernelGGL(packmod_k, dim3(2304), dim3(256), 0, stream, conv_w, sbuf, demod, wmod);

    // --- conv chain ---
    const dim3 cgrid(2048), cblk(256);
    // c1: t1 = prelu(conv(x, w1a))           XP -> PA
    hipLaunchKernelGGL((mconv_k<0, 0>), cgrid, cblk, 0, stream,
        XPH, XPL, (const char*)(wfix + 0 * 73728), alpha1, (const ushort*)nullptr, (const ushort*)nullptr,
        PAH, PAL, (float*)nullptr, zb);
    // c2: h1 = x + conv(t1, w1b)             PA -> PB  (resid XP)
    hipLaunchKernelGGL((mconv_k<1, 0>), cgrid, cblk, 0, stream,
        PAH, PAL, (const char*)(wfix + 1 * 73728), (const float*)nullptr, XPH, XPL,
        PBH, PBL, (float*)nullptr, zb);
    // c3: t2 = prelu(conv(h1, w2a))          PB -> PA
    hipLaunchKernelGGL((mconv_k<0, 0>), cgrid, cblk, 0, stream,
        PBH, PBL, (const char*)(wfix + 2 * 73728), alpha2, (const ushort*)nullptr, (const ushort*)nullptr,
        PAH, PAL, (float*)nullptr, zb);
    // c4: h2 = h1 + conv(t2, w2b)            PA -> PB  (resid PB, in-place same-index)
    hipLaunchKernelGGL((mconv_k<1, 0>), cgrid, cblk, 0, stream,
        PAH, PAL, (const char*)(wfix + 3 * 73728), (const float*)nullptr, PBH, PBL,
        PBH, PBL, (float*)nullptr, zb);
    // c5: out = fused_lrelu(modconv(h2)+b)   PB -> out (NCHW fp32)
    hipLaunchKernelGGL((mconv_k<2, 1>), cgrid, cblk, 0, stream,
        PBH, PBL, (const char*)wmod, fused_b, (const ushort*)nullptr, (const ushort*)nullptr,
        (ushort*)nullptr, (ushort*)nullptr, out, zb);
}

// Round 5
// 929.209 us; speedup vs baseline: 1.8920x; 1.8920x over previous
//
#include <hip/hip_runtime.h>
#include <hip/hip_bf16.h>
#include <math.h>

#define BB 8
#define SS 512
#define LIN_SCALE 0.044194173824159216f   // 1/sqrt(512)
#define CONV_SCALE 0.041666666666666664f  // 1/sqrt(64*9)
#define SQRT2 1.4142135623730951f

typedef __attribute__((ext_vector_type(8))) short short8;
typedef __attribute__((ext_vector_type(16))) float f32x16;

__device__ __forceinline__ ushort bf16h(float v) {
    unsigned u = __float_as_uint(v);
    return (ushort)((u + 0x7fffu + ((u >> 16) & 1u)) >> 16);
}
__device__ __forceinline__ void splitv(float v, ushort& h, ushort& l) {
    h = bf16h(v);
    l = bf16h(v - __uint_as_float((unsigned)h << 16));
}
__device__ __forceinline__ float b2f(ushort u) { return __uint_as_float((unsigned)u << 16); }

// ---------------------------------------------------------------------------
// prep kernels
// ---------------------------------------------------------------------------
__global__ void zero_k(float* z) { z[threadIdx.x] = 0.f; }   // 64 thr -> 256 B

// NCHW fp32 -> channels-last bf16 hi/lo planes
__global__ __launch_bounds__(256) void tocl_k(const float* __restrict__ x,
                                              ushort* __restrict__ oH, ushort* __restrict__ oL) {
    __shared__ float tile[64][65];
    const int blk = blockIdx.x;                  // 8*256*4
    const int b = blk >> 10, rem = blk & 1023;
    const int y = rem >> 2, x0 = (rem & 3) << 6;
    const int tid = threadIdx.x, lane = tid & 63, g = tid >> 6;
    const float* xb = x + ((size_t)b << 22) + (y << 8) + x0;
    #pragma unroll
    for (int i = 0; i < 16; ++i) {
        int c = i * 4 + g;
        tile[c][lane] = xb[((size_t)c << 16) + lane];
    }
    __syncthreads();
    const size_t pixbase = ((size_t)b << 16) + (y << 8) + x0;
    #pragma unroll
    for (int i = 0; i < 16; ++i) {
        int xx = i * 4 + g;
        ushort h, l; splitv(tile[lane][xx], h, l);
        size_t idx = (pixbase + xx) * 64 + lane;
        oH[idx] = h; oL[idx] = l;
    }
}

// Weight image layout (ushort index):
// i = (((((c*3+dx)*3+dy)*2+pl)*64+co)*2+lh)*8 + e
// cin = c*16 + lh*8 + e ; tap = dy*3+dx ; pl: 0=H 1=L.  73728 ushorts.
__device__ __forceinline__ void wdecode(int i, int& c, int& tap, int& co, int& ci, int& pl) {
    int e = i & 7;  int t = i >> 3;
    int lh = t & 1; t >>= 1;
    co = t & 63;    t >>= 6;
    pl = t & 1;     t >>= 1;
    int dy = t % 3; t /= 3;
    int dx = t % 3; t /= 3;
    c = t;
    ci = c * 16 + lh * 8 + e;
    tap = dy * 3 + dx;
}

__global__ void packw_k(const float* __restrict__ w, ushort* __restrict__ img) {
    int i = blockIdx.x * 256 + threadIdx.x;      // 73728
    if (i >= 73728) return;
    int c, tap, co, ci, pl;
    wdecode(i, c, tap, co, ci, pl);
    ushort h, l; splitv(w[(co * 64 + ci) * 9 + tap], h, l);
    img[i] = pl ? l : h;
}

__global__ void style_s_k(const float* __restrict__ style, const float* __restrict__ mod_w,
                          const float* __restrict__ mod_b, float* __restrict__ sbuf) {
    int tid = threadIdx.x;                       // 512
    int b = tid >> 6, cin = tid & 63;
    float acc = 0.f;
    for (int j = 0; j < SS; ++j) acc += style[b * SS + j] * mod_w[cin * SS + j];
    sbuf[b * 64 + cin] = acc * LIN_SCALE + mod_b[cin];
}

__global__ void demod_k(const float* __restrict__ conv_w, const float* __restrict__ sbuf,
                        float* __restrict__ demod) {
    int tid = threadIdx.x;                       // 512
    int b = tid >> 6, cout = tid & 63;
    float sum = 0.f;
    for (int cin = 0; cin < 64; ++cin) {
        float m = CONV_SCALE * sbuf[b * 64 + cin];
        const float* wp = conv_w + (cout * 64 + cin) * 9;
        #pragma unroll
        for (int k = 0; k < 9; ++k) { float v = wp[k] * m; sum += v * v; }
    }
    demod[b * 64 + cout] = 1.0f / sqrtf(sum + 1e-8f);
}

__global__ void packmod_k(const float* __restrict__ conv_w, const float* __restrict__ sbuf,
                          const float* __restrict__ demod, ushort* __restrict__ img) {
    int i = blockIdx.x * 256 + threadIdx.x;      // 589824
    if (i >= 589824) return;
    int b = i / 73728, ii = i % 73728;
    int c, tap, co, ci, pl;
    wdecode(ii, c, tap, co, ci, pl);
    float v = CONV_SCALE * conv_w[(co * 64 + ci) * 9 + tap] * sbuf[b * 64 + ci] * demod[b * 64 + co];
    ushort h, l; splitv(v, h, l);
    img[i] = pl ? l : h;
}

// ---------------------------------------------------------------------------
// MFMA conv: 3x3 C64->C64 SAME. Inputs: pre-split bf16 H/L channels-last.
// Block 256 thr = 4 waves; tile 8 rows x 32 px; all 64 couts; wave wv owns
// rows 2wv..2wv+1 (2 N-frags) x 2 M-frags. K chunked 16 cins.
// Weights: global->VGPR per dx-phase (12x16B, L2-resident), NO weight LDS.
// Input: DMA double-buffered LDS (21760 B/chunk), conflict-free granule
// permutation phi(p,s)=4p+(s^(p&3)), halo granules at 1280+.
// EPI: 0 = PReLU->pair, 1 = +resid(pair)->pair, 2 = fusedLReLU->NCHW fp32.
// ---------------------------------------------------------------------------
#define GLDS(gsrc, ldst) __builtin_amdgcn_global_load_lds( \
    (const __attribute__((address_space(1))) unsigned int*)(gsrc), \
    (__attribute__((address_space(3))) unsigned int*)(ldst), 16, 0, 0)

#define VWAIT0 asm volatile("s_waitcnt vmcnt(0)" ::: "memory")
#define BAR    __builtin_amdgcn_s_barrier()
#define SCB    __builtin_amdgcn_sched_barrier(0)

template <int EPI, int PERB>
__global__ __launch_bounds__(256, 2)
void mconv_k(const ushort* __restrict__ inH, const ushort* __restrict__ inL,
             const ushort* __restrict__ wimg, const float* __restrict__ aux,
             const ushort* __restrict__ rH, const ushort* __restrict__ rL,
             ushort* __restrict__ oH, ushort* __restrict__ oL,
             float* __restrict__ onchw, const ushort* __restrict__ zb) {
    __shared__ __align__(16) char lds[43520];    // 2 x 21760 B input chunk buffers
    const int tid = threadIdx.x;
    const int orig = blockIdx.x;
    const int blk = (orig & 7) * 256 + (orig >> 3);   // XCD swizzle (2048 % 8 == 0)
    const int b = blk >> 8, t8 = blk & 255;
    const int y0 = (t8 >> 3) << 3, x0 = (t8 & 7) << 5;
    const int wv = tid >> 6, l = tid & 63, ln = l & 31, lh = l >> 5;

    const ushort* wsrc = wimg + (PERB ? (size_t)b * 73728 : 0);

    f32x16 acc[2][2];
    #pragma unroll
    for (int m = 0; m < 2; ++m)
        #pragma unroll
        for (int j = 0; j < 2; ++j) acc[m][j] = (f32x16)(0.0f);

    // ---- DMA stage of one 16-cin chunk into buffer bsel ----
#define ISSUE_DMA(cc, bsel) { \
    const int c0_ = (cc) * 16; \
    char* bufb_ = lds + (bsel) * 21760; \
    _Pragma("unroll") \
    for (int r_ = 0; r_ < 5; ++r_) { \
        int g_ = r_ * 256 + tid; \
        int p_ = g_ >> 2, sp_ = g_ & 3; \
        int s_ = sp_ ^ (p_ & 3); \
        int pl_ = s_ >> 1, kh_ = s_ & 1; \
        int trow_ = p_ >> 5, px_ = p_ & 31; \
        int gy_ = y0 - 1 + trow_; \
        const ushort* base_ = pl_ ? inL : inH; \
        const ushort* src_ = ((unsigned)gy_ < 256u) \
            ? base_ + ((((size_t)b << 16) + ((size_t)gy_ << 8) + (x0 + px_)) << 6) + c0_ + kh_ * 8 \
            : zb; \
        GLDS(src_, bufb_ + r_ * 4096 + (tid & 192) * 16); \
    } \
    if (tid < 80) { \
        int sp_ = tid & 3, q_ = tid >> 2; \
        int trow_ = q_ % 10, side_ = q_ / 10; \
        int s_ = sp_ ^ (trow_ & 3); \
        int pl_ = s_ >> 1, kh_ = s_ & 1; \
        int gy_ = y0 - 1 + trow_; \
        int gx_ = side_ ? x0 + 32 : x0 - 1; \
        const ushort* base_ = pl_ ? inL : inH; \
        const ushort* src_ = (((unsigned)gy_ < 256u) & ((unsigned)gx_ < 256u)) \
            ? base_ + ((((size_t)b << 16) + ((size_t)gy_ << 8) + gx_) << 6) + c0_ + kh_ * 8 \
            : zb; \
        GLDS(src_, bufb_ + 20480 + (tid & 192) * 16); \
    } }

    // prologue: stage chunk 0, full drain once
    ISSUE_DMA(0, 0);
    VWAIT0; BAR; SCB;

    #pragma unroll
    for (int c = 0; c < 4; ++c) {
        const char* bufb = lds + (c & 1) * 21760;
        #pragma unroll
        for (int dx = 0; dx < 3; ++dx) {
            // ---- A: weights for this dx-phase, global -> VGPR ----
            short8 aH[3][2], aL[3][2];
            #pragma unroll
            for (int dy = 0; dy < 3; ++dy)
                #pragma unroll
                for (int m = 0; m < 2; ++m) {
                    const ushort* ab = wsrc + (((c * 3 + dx) * 3 + dy) * 2) * 1024
                                       + (m * 32 + ln) * 16 + lh * 8;
                    aH[dy][m] = *(const short8*)ab;
                    aL[dy][m] = *(const short8*)(ab + 1024);
                }
            // next chunk's DMA: issued AFTER dx0's A-loads (A-wait leaves DMA in flight)
            if (dx == 0 && c < 3) { ISSUE_DMA(c + 1, (c & 1) ^ 1); }

            // ---- B: 4 input rows (HL) from LDS ----
            short8 bH[4], bL[4];
            #pragma unroll
            for (int r = 0; r < 4; ++r) {
                const int trow = 2 * wv + r;
                const int px = ln + dx - 1;
                int offH, offL;
                if (px < 0 || px > 31) {
                    const int side = (px > 31) ? 1 : 0;
                    const int hb = 1280 + (side * 10 + trow) * 4;
                    offH = (hb + (lh ^ (trow & 3))) * 16;
                    offL = (hb + ((2 + lh) ^ (trow & 3))) * 16;
                } else {
                    const int p = trow * 32 + px;
                    offH = (4 * p + (lh ^ (p & 3))) * 16;
                    offL = (4 * p + ((2 + lh) ^ (p & 3))) * 16;
                }
                bH[r] = *(const short8*)(bufb + offH);
                bL[r] = *(const short8*)(bufb + offL);
            }
            // ---- MFMA: 36 per dx-phase ----
            #pragma unroll
            for (int dy = 0; dy < 3; ++dy)
                #pragma unroll
                for (int j = 0; j < 2; ++j) {
                    const int r = j + dy;
                    acc[0][j] = __builtin_amdgcn_mfma_f32_32x32x16_bf16(aH[dy][0], bH[r], acc[0][j], 0, 0, 0);
                    acc[0][j] = __builtin_amdgcn_mfma_f32_32x32x16_bf16(aH[dy][0], bL[r], acc[0][j], 0, 0, 0);
                    acc[0][j] = __builtin_amdgcn_mfma_f32_32x32x16_bf16(aL[dy][0], bH[r], acc[0][j], 0, 0, 0);
                    acc[1][j] = __builtin_amdgcn_mfma_f32_32x32x16_bf16(aH[dy][1], bH[r], acc[1][j], 0, 0, 0);
                    acc[1][j] = __builtin_amdgcn_mfma_f32_32x32x16_bf16(aH[dy][1], bL[r], acc[1][j], 0, 0, 0);
                    acc[1][j] = __builtin_amdgcn_mfma_f32_32x32x16_bf16(aL[dy][1], bH[r], acc[1][j], 0, 0, 0);
                }
        }
        if (c < 3) { VWAIT0; SCB; BAR; SCB; }
    }
#undef ISSUE_DMA

    // ---- epilogue: C/D col = ln(px), row = 8q + 4lh + (0..3), +32m ----
    #pragma unroll
    for (int m = 0; m < 2; ++m)
        #pragma unroll
        for (int j = 0; j < 2; ++j) {
            const int yo = y0 + 2 * wv + j;
            const size_t pix = ((size_t)b << 16) + ((size_t)yo << 8) + x0 + ln;
            #pragma unroll
            for (int q = 0; q < 4; ++q) {
                const int co0 = m * 32 + 8 * q + 4 * lh;
                float v0 = acc[m][j][4 * q + 0], v1 = acc[m][j][4 * q + 1];
                float v2 = acc[m][j][4 * q + 2], v3 = acc[m][j][4 * q + 3];
                if (EPI == 0) {
                    float4 al = *(const float4*)(aux + co0);
                    v0 = v0 > 0.f ? v0 : al.x * v0;
                    v1 = v1 > 0.f ? v1 : al.y * v1;
                    v2 = v2 > 0.f ? v2 : al.z * v2;
                    v3 = v3 > 0.f ? v3 : al.w * v3;
                } else if (EPI == 1) {
                    const size_t ca = pix * 64 + co0;
                    ushort4 rh = *(const ushort4*)(rH + ca);
                    ushort4 rl = *(const ushort4*)(rL + ca);
                    v0 += b2f(rh.x) + b2f(rl.x);
                    v1 += b2f(rh.y) + b2f(rl.y);
                    v2 += b2f(rh.z) + b2f(rl.z);
                    v3 += b2f(rh.w) + b2f(rl.w);
                } else {
                    float4 bi = *(const float4*)(aux + co0);
                    float ob;
                    ob = v0 + bi.x; v0 = (ob > 0.f ? ob : 0.2f * ob) * SQRT2;
                    ob = v1 + bi.y; v1 = (ob > 0.f ? ob : 0.2f * ob) * SQRT2;
                    ob = v2 + bi.z; v2 = (ob > 0.f ? ob : 0.2f * ob) * SQRT2;
                    ob = v3 + bi.w; v3 = (ob > 0.f ? ob : 0.2f * ob) * SQRT2;
                }
                if (EPI == 2) {
                    const size_t sp = ((size_t)yo << 8) + x0 + ln;
                    onchw[(((size_t)(b * 64 + co0 + 0)) << 16) + sp] = v0;
                    onchw[(((size_t)(b * 64 + co0 + 1)) << 16) + sp] = v1;
                    onchw[(((size_t)(b * 64 + co0 + 2)) << 16) + sp] = v2;
                    onchw[(((size_t)(b * 64 + co0 + 3)) << 16) + sp] = v3;
                } else {
                    ushort4 h4, l4;
                    splitv(v0, h4.x, l4.x); splitv(v1, h4.y, l4.y);
                    splitv(v2, h4.z, l4.z); splitv(v3, h4.w, l4.w);
                    const size_t ca = pix * 64 + co0;
                    *(ushort4*)(oH + ca) = h4;
                    *(ushort4*)(oL + ca) = l4;
                }
            }
        }
}

// ---------------------------------------------------------------------------
// Host launch
// ---------------------------------------------------------------------------
extern "C" void kernel_launch(void* const* d_in, const int* in_sizes, int n_in,
                              void* d_out, int out_size, void* d_ws, size_t ws_size,
                              hipStream_t stream) {
    const float* x       = (const float*)d_in[0];
    const float* style   = (const float*)d_in[1];
    const float* w1a     = (const float*)d_in[2];
    const float* alpha1  = (const float*)d_in[3];
    const float* w1b     = (const float*)d_in[4];
    const float* w2a     = (const float*)d_in[5];
    const float* alpha2  = (const float*)d_in[6];
    const float* w2b     = (const float*)d_in[7];
    const float* mod_w   = (const float*)d_in[8];
    const float* mod_b   = (const float*)d_in[9];
    const float* conv_w  = (const float*)d_in[10];
    const float* fused_b = (const float*)d_in[11];
    float* out = (float*)d_out;

    char* ws = (char*)d_ws;
    float*  zbf   = (float*)ws;                  // 256 B zero buffer
    float*  sbuf  = (float*)(ws + 256);          // 512 f
    float*  demod = (float*)(ws + 2304);         // 512 f
    ushort* wfix  = (ushort*)(ws + 4352);        // 4 x 147456 B images
    ushort* wmod  = (ushort*)(ws + 594176);      // 8 x 147456 B
    char*   pl    = ws + 1774080;
    const size_t PAIRB = 134217728ull;           // one H+L plane pair (bytes)
    const size_t PLEL  = 33554432ull;            // elements per plane

    ushort* XPH = (ushort*)pl;             ushort* XPL = XPH + PLEL;
    ushort* PBH = (ushort*)(pl + PAIRB);   ushort* PBL = PBH + PLEL;
    ushort *PAH, *PAL;
    if (ws_size >= 1774080ull + 3 * PAIRB) {
        PAH = (ushort*)(pl + 2 * PAIRB); PAL = PAH + PLEL;
    } else {
        PAH = (ushort*)d_out; PAL = PAH + PLEL;  // d_out hosts PA; rewritten by c5
    }
    const ushort* zb = (const ushort*)zbf;

    // --- prep ---
    hipLaunchKernelGGL(zero_k, dim3(1), dim3(64), 0, stream, zbf);
    hipLaunchKernelGGL(tocl_k, dim3(BB * 1024), dim3(256), 0, stream, x, XPH, XPL);
    hipLaunchKernelGGL(packw_k, dim3(288), dim3(256), 0, stream, w1a, wfix + 0 * 73728);
    hipLaunchKernelGGL(packw_k, dim3(288), dim3(256), 0, stream, w1b, wfix + 1 * 73728);
    hipLaunchKernelGGL(packw_k, dim3(288), dim3(256), 0, stream, w2a, wfix + 2 * 73728);
    hipLaunchKernelGGL(packw_k, dim3(288), dim3(256), 0, stream, w2b, wfix + 3 * 73728);
    hipLaunchKernelGGL(style_s_k, dim3(1), dim3(512), 0, stream, style, mod_w, mod_b, sbuf);
    hipLaunchKernelGGL(demod_k, dim3(1), dim3(512), 0, stream, conv_w, sbuf, demod);
    hipLaunchKernelGGL(packmod_k, dim3(2304), dim3(256), 0, stream, conv_w, sbuf, demod, wmod);

    // --- conv chain ---
    const dim3 cgrid(2048), cblk(256);
    // c1: t1 = prelu(conv(x, w1a))           XP -> PA
    hipLaunchKernelGGL((mconv_k<0, 0>), cgrid, cblk, 0, stream,
        XPH, XPL, wfix + 0 * 73728, alpha1, (const ushort*)nullptr, (const ushort*)nullptr,
        PAH, PAL, (float*)nullptr, zb);
    // c2: h1 = x + conv(t1, w1b)             PA -> PB  (resid XP)
    hipLaunchKernelGGL((mconv_k<1, 0>), cgrid, cblk, 0, stream,
        PAH, PAL, wfix + 1 * 73728, (const float*)nullptr, XPH, XPL,
        PBH, PBL, (float*)nullptr, zb);
    // c3: t2 = prelu(conv(h1, w2a))          PB -> PA
    hipLaunchKernelGGL((mconv_k<0, 0>), cgrid, cblk, 0, stream,
        PBH, PBL, wfix + 2 * 73728, alpha2, (const ushort*)nullptr, (const ushort*)nullptr,
        PAH, PAL, (float*)nullptr, zb);
    // c4: h2 = h1 + conv(t2, w2b)            PA -> PB  (resid PB, in-place same-index)
    hipLaunchKernelGGL((mconv_k<1, 0>), cgrid, cblk, 0, stream,
        PAH, PAL, wfix + 3 * 73728, (const float*)nullptr, PBH, PBL,
        PBH, PBL, (float*)nullptr, zb);
    // c5: out = fused_lrelu(modconv(h2)+b)   PB -> out (NCHW fp32)
    hipLaunchKernelGGL((mconv_k<2, 1>), cgrid, cblk, 0, stream,
        PBH, PBL, wmod, fused_b, (const ushort*)nullptr, (const ushort*)nullptr,
        (ushort*)nullptr, (ushort*)nullptr, out, zb);
}